// Round 8
// baseline (551.610 us; speedup 1.0000x reference)
//
#include <hip/hip_runtime.h>

// MultiHeadSelfAttention: B=2, S=2048, E=768, H=12, D=64
// R20: flash = R19 LDS-free body + in-block split-K for TLP. R19 showed the
//      right structure (no LDS pipe, no barriers) but 1-wave blocks gave
//      1.5 waves/SIMD (Occupancy 12%) -> latency chain exposed. Now: block =
//      4 waves, one 32-row q-unit; each wave does 8 of 32 K-tiles (same
//      total L2 traffic, 786MB), partials merged ONCE per block through
//      25KB LDS (not global - R17's mistake). VGPR<=128 via
//      launch_bounds(256,4) -> 4 waves/SIMD. prep/gemmQKV/gemm2 unchanged.

typedef __bf16 bf16_t;
typedef bf16_t bf16x8 __attribute__((ext_vector_type(8)));
typedef bf16_t bf16x4 __attribute__((ext_vector_type(4)));
typedef float f32x4 __attribute__((ext_vector_type(4)));
typedef _Float16 f16x4 __attribute__((ext_vector_type(4)));
typedef _Float16 f16x8 __attribute__((ext_vector_type(8)));
typedef __fp16 hf2 __attribute__((ext_vector_type(2)));

#define SC2 0.1803368801111137f  // 0.125 * log2(e): qk-scale folded into exp2
#define DEFER_THR 44.0f          // ~8/SC2: defer-max rescale threshold (T13)

__device__ __forceinline__ float bf2f(unsigned short u) {
  union { unsigned int i; float f; } x;
  x.i = ((unsigned int)u) << 16;
  return x.f;
}

__device__ __forceinline__ float fexp2(float x) {
  return __builtin_amdgcn_exp2f(x);  // raw v_exp_f32; args <= 8 here, FTZ exact
}

__device__ __forceinline__ void glds16(const bf16_t* g, bf16_t* l) {
  __builtin_amdgcn_global_load_lds(
      (const __attribute__((address_space(1))) void*)g,
      (__attribute__((address_space(3))) void*)l, 16, 0, 0);
}

// dtype probe: wave examines first 1024 u16 words of x. fp32 data => low
// halves carry random mantissa bits => wild bf16 exponents.
__device__ __forceinline__ int detect_bf16_flag(const unsigned short* x) {
  const int lane = threadIdx.x & 63;
  const uint4* p = (const uint4*)x;
  uint4 a = p[lane * 2];
  uint4 b = p[lane * 2 + 1];
  unsigned int w[8] = {a.x, a.y, a.z, a.w, b.x, b.y, b.z, b.w};
  unsigned int big = 0;
#pragma unroll
  for (int i = 0; i < 8; i++) {
    unsigned int e0 = (w[i] >> 7) & 0xFF, e1 = (w[i] >> 23) & 0xFF;
    big |= (e0 > 0x88u) | (e1 > 0x88u);
  }
  unsigned long long bal = __ballot(big != 0u);
  return bal == 0ULL ? 1 : 0;  // 1 => bf16 inputs
}

// ---------------------------------------------------------------- fused prep
__global__ void k_prep(const void* __restrict__ x, const void* __restrict__ mask,
                       const void* __restrict__ Wq, const void* __restrict__ Wk,
                       const void* __restrict__ Wv, const void* __restrict__ Wo,
                       bf16_t* __restrict__ xb, bf16_t* __restrict__ wqkvT,
                       bf16_t* __restrict__ woT, int* __restrict__ mflags) {
  __shared__ float ts[32][33];
  __shared__ int snz;
  const int blk = blockIdx.x;
  const int f = detect_bf16_flag((const unsigned short*)x);

  if (blk < 1536) {  // ---- ingest x (fp32 only; bf16 path reads x directly)
    if (f) return;
    int i = blk * 256 + threadIdx.x;
    const float* xf = (const float*)x + (size_t)i * 8;
    bf16x8 v;
#pragma unroll
    for (int j = 0; j < 8; j++) v[j] = (bf16_t)xf[j];
    *(bf16x8*)(xb + (size_t)i * 8) = v;
  } else if (blk < 3840) {  // ---- W transpose (4 matrices x 24x24 tiles)
    const int t = blk - 1536;
    const int z = t / 576, r = t % 576, kt = r / 24, nt = r % 24;
    const void* wsrc = (z == 0) ? Wq : (z == 1) ? Wk : (z == 2) ? Wv : Wo;
    bf16_t* dst = (z < 3) ? (wqkvT + (size_t)z * 768 * 768) : woT;
    const int c = threadIdx.x & 31, r0 = threadIdx.x >> 5;
#pragma unroll
    for (int i = 0; i < 4; i++) {
      int kr = kt * 32 + r0 + i * 8;
      float v;
      if (f) v = bf2f(((const unsigned short*)wsrc)[(size_t)kr * 768 + nt * 32 + c]);
      else   v = ((const float*)wsrc)[(size_t)kr * 768 + nt * 32 + c];
      ts[r0 + i * 8][c] = v;
    }
    __syncthreads();
#pragma unroll
    for (int i = 0; i < 4; i++) {
      int nr = nt * 32 + r0 + i * 8;
      dst[(size_t)nr * 768 + kt * 32 + c] = (bf16_t)ts[c][r0 + i * 8];
    }
  } else {  // ---- mask nonzero flag per 128x128 tile, uint4 loads
    const int t = blk - 3840;
    const int qt = t >> 4, ktm = t & 15;
    if (threadIdx.x == 0) snz = 0;
    __syncthreads();
    unsigned int nz = 0;
    if (f) {
#pragma unroll
      for (int i = 0; i < 8; i++) {
        int uidx = i * 256 + threadIdx.x;
        int row = uidx >> 4, col = uidx & 15;
        const uint4* p = (const uint4*)((const char*)mask +
            ((size_t)(qt * 128 + row) * 2048 + ktm * 128) * 2 + col * 16);
        uint4 v = *p;
        nz |= ((v.x | v.y | v.z | v.w) & 0x7fff7fffu);
      }
    } else {
#pragma unroll
      for (int i = 0; i < 16; i++) {
        int uidx = i * 256 + threadIdx.x;
        int row = uidx >> 5, col = uidx & 31;
        const uint4* p = (const uint4*)((const char*)mask +
            ((size_t)(qt * 128 + row) * 2048 + ktm * 128) * 4 + col * 16);
        uint4 v = *p;
        nz |= ((v.x | v.y | v.z | v.w) & 0x7fffffffu);
      }
    }
    if (nz) snz = 1;
    __syncthreads();
    if (threadIdx.x == 0) mflags[qt * 16 + ktm] = snz;
  }
}

// ------------------------------------------------------------------ QKV GEMM
// C[4096 x 2304] = A * wqkvT^T, 128x128 tile, BK=32 double-buffered with
// prefetch-before-compute. Epilogues emit flash-ready tiled layouts:
//   Kd: per (b,h,64-key group) 8KB block = permuted-slot fragment image
//   Vt: per (b,h,64-key tile) 8KB block, [64d][128B row ^ ((d&7)<<4)]
__global__ __launch_bounds__(256, 3) void k_gemmQKV(
    const bf16_t* __restrict__ xb, const bf16_t* __restrict__ Bm,
    bf16_t* __restrict__ Qd, char* __restrict__ Kd, char* __restrict__ Vt,
    const unsigned short* __restrict__ xdet) {
  __shared__ __align__(16) char smem[32768];  // A slots @0,8192 | B @16384,24576
  _Float16* Tb = (_Float16*)smem;             // V epilogue reuse (17.4KB)

  const int f = detect_bf16_flag(xdet);
  const bf16_t* A = f ? (const bf16_t*)xdet : xb;

  const int tid = threadIdx.x;
  const int n0 = blockIdx.x * 128, m0 = blockIdx.y * 128;
  const int r = tid >> 2, c8 = (tid & 3) << 3;
  const bf16_t* Ag = A + (size_t)(m0 + r) * 768 + c8;
  const bf16_t* Bg = Bm + (size_t)(n0 + r) * 768 + c8;
  const int wid = tid >> 6, lane = tid & 63;
  const int wm = (wid >> 1) << 6, wn = (wid & 1) << 6;
  const int lr = lane & 15, quad = lane >> 4, lk = quad << 3, g4 = quad << 2;

  f32x4 acc[4][4];
  const f32x4 z = {0.f, 0.f, 0.f, 0.f};
#pragma unroll
  for (int i = 0; i < 4; i++)
#pragma unroll
    for (int j = 0; j < 4; j++) acc[i][j] = z;

  {  // stage k0=0 -> slot 0
    bf16_t* A0 = (bf16_t*)smem;
    bf16_t* B0 = (bf16_t*)(smem + 16384);
    glds16(Ag, A0 + wid * 512);
    glds16(Ag + (size_t)64 * 768, A0 + 2048 + wid * 512);
    glds16(Bg, B0 + wid * 512);
    glds16(Bg + (size_t)64 * 768, B0 + 2048 + wid * 512);
  }
  __syncthreads();

  for (int s = 0; s < 24; s++) {
    if (s < 23) {  // prefetch s+1 into other slot (overlaps compute below)
      const int k0 = (s + 1) * 32;
      bf16_t* An = (bf16_t*)(smem + ((s + 1) & 1) * 8192);
      bf16_t* Bn = (bf16_t*)(smem + 16384 + ((s + 1) & 1) * 8192);
      glds16(Ag + k0, An + wid * 512);
      glds16(Ag + (size_t)64 * 768 + k0, An + 2048 + wid * 512);
      glds16(Bg + k0, Bn + wid * 512);
      glds16(Bg + (size_t)64 * 768 + k0, Bn + 2048 + wid * 512);
    }
    const bf16_t* As = (const bf16_t*)(smem + (s & 1) * 8192);
    const bf16_t* Bs = (const bf16_t*)(smem + 16384 + (s & 1) * 8192);
    bf16x8 af[4], bf_[4];
#pragma unroll
    for (int t = 0; t < 4; t++) af[t]  = *(const bf16x8*)&As[(wm + t * 16 + lr) * 32 + lk];
#pragma unroll
    for (int t = 0; t < 4; t++) bf_[t] = *(const bf16x8*)&Bs[(wn + t * 16 + lr) * 32 + lk];
#pragma unroll
    for (int i = 0; i < 4; i++)
#pragma unroll
      for (int j = 0; j < 4; j++)
        acc[i][j] = __builtin_amdgcn_mfma_f32_16x16x32_bf16(af[i], bf_[j], acc[i][j], 0, 0, 0);
    __syncthreads();  // joins waves + drains this iter's DMA (issued pre-compute)
  }

  if (n0 < 768) {  // Q: natural [seq][d] scatter
    const int bb = m0 >> 11;
#pragma unroll
    for (int i = 0; i < 4; i++)
#pragma unroll
      for (int j = 0; j < 4; j++) {
        const int rc = n0 + wn + j * 16 + lr;
        const int hh = rc >> 6, dd = rc & 63;
        const size_t base = (((size_t)bb * 12 + hh) * 2048) * 64 + dd;
#pragma unroll
        for (int reg = 0; reg < 4; reg++) {
          const int s = (m0 & 2047) + wm + i * 16 + g4 + reg;
          Qd[base + (size_t)s * 64] = (bf16_t)acc[i][j][reg];
        }
      }
  } else if (n0 < 1536) {  // K: permuted-slot tiled layout (flash fragment image)
    const int nb = n0 - 768;
    const int bb = m0 >> 11;
    const int g = ((m0 & 2047) + wm) >> 6;  // 64-key group
#pragma unroll
    for (int i = 0; i < 4; i++) {
#pragma unroll
      for (int j = 0; j < 4; j++) {
        const int rc = nb + wn + j * 16 + lr;
        const int hh = rc >> 6, dd = rc & 63;
        const size_t tbase = ((size_t)((bb * 12 + hh) * 32 + g)) << 13;
        const int doff = ((dd >> 5) << 10) + (((dd >> 3) & 3) << 8) + ((dd & 7) << 1);
#pragma unroll
        for (int reg = 0; reg < 4; reg++) {
          // slot sigma(w), w = 16i + 4*quad + reg (within-64 key index)
          const int sig = ((i >> 1) << 5) + ((quad & 1) << 4) +
                          (((((i & 1) << 1) | (quad >> 1))) << 2) + reg;
          *(bf16_t*)(Kd + tbase + ((sig >> 4) << 11) + ((sig & 15) << 4) + doff) =
              (bf16_t)acc[i][j][reg];
        }
      }
    }
  } else {  // V: LDS transpose -> tiled swizzled [64d][128B^swz] blocks
    const int bb = m0 >> 11;
#pragma unroll
    for (int half = 0; half < 2; half++) {
      if ((wid & 1) == half) {
#pragma unroll
        for (int j = 0; j < 4; j++) {
          const int d_l = j * 16 + lr;
#pragma unroll
          for (int i = 0; i < 4; i++)
#pragma unroll
            for (int reg = 0; reg < 4; reg++)
              Tb[d_l * 136 + wm + i * 16 + g4 + reg] = (_Float16)acc[i][j][reg];
        }
      }
      __syncthreads();
      const int row = tid >> 2, cc = (tid & 3) * 32;  // row = d (0..63)
      const int vcol = (n0 - 1536) + half * 64 + row;
      const int hh = vcol >> 6;
      const int g = ((m0 & 2047) + cc) >> 6;          // 64-key tile
      const int koff2 = (cc & 63) * 2;                // 0 or 64 bytes
      char* vb = Vt + (((size_t)((bb * 12 + hh) * 32 + g)) << 13) + (row << 7);
#pragma unroll
      for (int u = 0; u < 4; u++)
        *(uint4*)(vb + ((koff2 + u * 16) ^ ((row & 7) << 4))) =
            *(const uint4*)&Tb[row * 136 + cc + u * 8];
      __syncthreads();
    }
  }
}

// ----------------------------------------------------------- flash attention
// R20: 1536 blocks x 256 thr (4 waves). Block owns one (bh, 32-q-row) unit;
// wave w handles K-tiles [w*8, w*8+8) with the R19 LDS-free body (K/V
// fragments global->VGPR from pre-permuted layouts, K prefetch 1 ahead).
// Partials (m,l,O) merged once per block through LDS (LSE-combine, exact).
__global__ __launch_bounds__(256, 4) void k_flash(
    const bf16_t* __restrict__ Qd, const char* __restrict__ Kd,
    const char* __restrict__ Vt, const void* __restrict__ mask,
    const int* __restrict__ mflags, const unsigned short* __restrict__ xdet,
    bf16_t* __restrict__ attn) {
  __shared__ float smO[3][32][64];      // waves 1-3 partial O, [elem][lane]
  __shared__ float smML[3][2][16][2];   // waves 1-3, frag A/B, row, (m,l)

  const int tid = threadIdx.x, wid = tid >> 6, lane = tid & 63;
  const int lr = lane & 15, quad = lane >> 4, lk = quad << 3, g4 = quad << 2;

  const int lin = blockIdx.x;
  const int gx = lin & 7, ww = lin >> 3;          // ww 0..191
  const int hb = gx * 3 + (ww >> 6);              // 3 bh per XCD (L2 affinity)
  const int h = hb % 12, bb = hb / 12;
  const int u = ww & 63;                          // 32-row q-unit
  const int q0 = u * 32;
  const int wtile = wid << 3;                     // this wave's first K-tile

  const size_t bh = (size_t)bb * 12 + h;
  const char* Kw = Kd + (bh << 18) + ((size_t)wtile << 13);
  const char* Vw = Vt + (bh << 18) + ((size_t)wtile << 13);

  const bf16_t* Qh = Qd + bh * 2048 * 64;
  const int mbf = detect_bf16_flag(xdet);
  const int* mfrow = mflags + (u >> 2) * 16;
  int mbits = 0;
#pragma unroll
  for (int t = 0; t < 16; t++) mbits |= (mfrow[t] != 0) << t;

  const bf16x8 qfA0 = *(const bf16x8*)&Qh[(size_t)(q0 + lr) * 64 + lk];
  const bf16x8 qfA1 = *(const bf16x8*)&Qh[(size_t)(q0 + lr) * 64 + 32 + lk];
  const bf16x8 qfB0 = *(const bf16x8*)&Qh[(size_t)(q0 + 16 + lr) * 64 + lk];
  const bf16x8 qfB1 = *(const bf16x8*)&Qh[(size_t)(q0 + 16 + lr) * 64 + 32 + lk];

  f16x8 ones8;
#pragma unroll
  for (int j = 0; j < 8; j++) ones8[j] = (_Float16)1.f;

  // V fragment offsets (per-lane constant, within 8KB tile)
  const int vxo0 = (quad * 16) ^ ((lr & 7) << 4);
  const int vxo1 = (64 + quad * 16) ^ ((lr & 7) << 4);

  const f32x4 z = {0.f, 0.f, 0.f, 0.f};
  f32x4 otA[4], otB[4];
#pragma unroll
  for (int dt = 0; dt < 4; dt++) { otA[dt] = z; otB[dt] = z; }
  float mA = -1e30f, lA = 0.f, mB = -1e30f, lB = 0.f;

  bf16x8 kfP[8], kfQ[8];
  {  // prologue: K fragments for this wave's tile 0
#pragma unroll
    for (int ct = 0; ct < 4; ct++) {
      kfP[ct * 2]     = *(const bf16x8*)(Kw + ct * 2048 + lane * 16);
      kfP[ct * 2 + 1] = *(const bf16x8*)(Kw + ct * 2048 + 1024 + lane * 16);
    }
  }

  // BODY(sl): V(sl) loads; K(sl+1)->KN; QK(sl) from KC; softmax A/B; PV.
#define FLASH_BODY(S, KC, KN)                                                \
  {                                                                          \
    const int sl_ = (S);                                                     \
    const char* Vt_ = Vw + ((size_t)sl_ << 13);                              \
    f16x8 vf[8];                                                             \
    _Pragma("unroll")                                                        \
    for (int c2 = 0; c2 < 2; c2++) {                                         \
      _Pragma("unroll")                                                      \
      for (int dt = 0; dt < 4; dt++)                                         \
        vf[c2 * 4 + dt] = *(const f16x8*)(Vt_ + (dt * 16 + lr) * 128 +       \
                                          (c2 ? vxo1 : vxo0));               \
    }                                                                        \
    if (sl_ + 1 < 8) {                                                       \
      const char* Kn_ = Kw + ((size_t)(sl_ + 1) << 13);                      \
      _Pragma("unroll")                                                      \
      for (int ct = 0; ct < 4; ct++) {                                       \
        KN[ct * 2]     = *(const bf16x8*)(Kn_ + ct * 2048 + lane * 16);      \
        KN[ct * 2 + 1] = *(const bf16x8*)(Kn_ + ct * 2048 + 1024 + lane * 16); \
      }                                                                      \
    }                                                                        \
    f32x4 svA[4], svB[4];                                                    \
    _Pragma("unroll")                                                        \
    for (int ct = 0; ct < 4; ct++) { svA[ct] = z; svB[ct] = z; }             \
    __builtin_amdgcn_s_setprio(1);                                           \
    _Pragma("unroll")                                                        \
    for (int ct = 0; ct < 4; ct++) {                                         \
      svA[ct] = __builtin_amdgcn_mfma_f32_16x16x32_bf16(KC[ct * 2], qfA0, svA[ct], 0, 0, 0); \
      svA[ct] = __builtin_amdgcn_mfma_f32_16x16x32_bf16(KC[ct * 2 + 1], qfA1, svA[ct], 0, 0, 0); \
      svB[ct] = __builtin_amdgcn_mfma_f32_16x16x32_bf16(KC[ct * 2], qfB0, svB[ct], 0, 0, 0); \
      svB[ct] = __builtin_amdgcn_mfma_f32_16x16x32_bf16(KC[ct * 2 + 1], qfB1, svB[ct], 0, 0, 0); \
    }                                                                        \
    __builtin_amdgcn_s_setprio(0);                                           \
    const int gt_ = wtile + sl_;                                             \
    if ((mbits >> (gt_ >> 1)) & 1) {                                         \
      _Pragma("unroll")                                                      \
      for (int ct = 0; ct < 4; ct++) {                                       \
        _Pragma("unroll")                                                    \
        for (int reg = 0; reg < 4; reg++) {                                  \
          const int kk = ((ct >> 1) << 5) + (quad << 3) + ((ct & 1) << 2) + reg; \
          size_t miA = (size_t)(q0 + lr) * 2048 + gt_ * 64 + kk;             \
          size_t miB = (size_t)(q0 + 16 + lr) * 2048 + gt_ * 64 + kk;        \
          float mvA = mbf ? bf2f(((const unsigned short*)mask)[miA])         \
                          : ((const float*)mask)[miA];                       \
          float mvB = mbf ? bf2f(((const unsigned short*)mask)[miB])         \
                          : ((const float*)mask)[miB];                       \
          svA[ct][reg] -= 8e9f * mvA;                                        \
          svB[ct][reg] -= 8e9f * mvB;                                        \
        }                                                                    \
      }                                                                      \
    }                                                                        \
    float tA = fmaxf(                                                        \
        fmaxf(fmaxf(fmaxf(svA[0][0], svA[0][1]), fmaxf(svA[0][2], svA[0][3])), \
              fmaxf(fmaxf(svA[1][0], svA[1][1]), fmaxf(svA[1][2], svA[1][3]))), \
        fmaxf(fmaxf(fmaxf(svA[2][0], svA[2][1]), fmaxf(svA[2][2], svA[2][3])), \
              fmaxf(fmaxf(svA[3][0], svA[3][1]), fmaxf(svA[3][2], svA[3][3])))); \
    float tB = fmaxf(                                                        \
        fmaxf(fmaxf(fmaxf(svB[0][0], svB[0][1]), fmaxf(svB[0][2], svB[0][3])), \
              fmaxf(fmaxf(svB[1][0], svB[1][1]), fmaxf(svB[1][2], svB[1][3]))), \
        fmaxf(fmaxf(fmaxf(svB[2][0], svB[2][1]), fmaxf(svB[2][2], svB[2][3])), \
              fmaxf(fmaxf(svB[3][0], svB[3][1]), fmaxf(svB[3][2], svB[3][3])))); \
    tA = fmaxf(tA, __shfl_xor(tA, 16));                                      \
    tA = fmaxf(tA, __shfl_xor(tA, 32));                                      \
    tB = fmaxf(tB, __shfl_xor(tB, 16));                                      \
    tB = fmaxf(tB, __shfl_xor(tB, 32));                                      \
    if (__ballot(tA > mA + DEFER_THR)) {                                     \
      const float mnew = fmaxf(mA, tA);                                      \
      const float alpha = fexp2((mA - mnew) * SC2);                          \
      _Pragma("unroll")                                                      \
      for (int dt = 0; dt < 4; dt++) {                                       \
        _Pragma("unroll")                                                    \
        for (int reg = 0; reg < 4; reg++) otA[dt][reg] *= alpha;             \
      }                                                                      \
      lA *= alpha; mA = mnew;                                                \
    }                                                                        \
    if (__ballot(tB > mB + DEFER_THR)) {                                     \
      const float mnew = fmaxf(mB, tB);                                      \
      const float alpha = fexp2((mB - mnew) * SC2);                          \
      _Pragma("unroll")                                                      \
      for (int dt = 0; dt < 4; dt++) {                                       \
        _Pragma("unroll")                                                    \
        for (int reg = 0; reg < 4; reg++) otB[dt][reg] *= alpha;             \
      }                                                                      \
      lB *= alpha; mB = mnew;                                                \
    }                                                                        \
    const float mSA = mA * SC2, mSB = mB * SC2;                              \
    f16x8 pbA[2], pbB[2];                                                    \
    _Pragma("unroll")                                                        \
    for (int c2 = 0; c2 < 2; c2++) {                                         \
      union { hf2 hh[4]; f16x8 v; } uA, uB;                                  \
      _Pragma("unroll")                                                      \
      for (int hh2 = 0; hh2 < 2; hh2++) {                                    \
        const int ct = c2 * 2 + hh2;                                         \
        float a0 = fexp2(fmaf(svA[ct][0], SC2, -mSA));                       \
        float a1 = fexp2(fmaf(svA[ct][1], SC2, -mSA));                       \
        float a2 = fexp2(fmaf(svA[ct][2], SC2, -mSA));                       \
        float a3 = fexp2(fmaf(svA[ct][3], SC2, -mSA));                       \
        float b0 = fexp2(fmaf(svB[ct][0], SC2, -mSB));                       \
        float b1 = fexp2(fmaf(svB[ct][1], SC2, -mSB));                       \
        float b2 = fexp2(fmaf(svB[ct][2], SC2, -mSB));                       \
        float b3 = fexp2(fmaf(svB[ct][3], SC2, -mSB));                       \
        uA.hh[hh2 * 2 + 0] = __builtin_amdgcn_cvt_pkrtz(a0, a1);             \
        uA.hh[hh2 * 2 + 1] = __builtin_amdgcn_cvt_pkrtz(a2, a3);             \
        uB.hh[hh2 * 2 + 0] = __builtin_amdgcn_cvt_pkrtz(b0, b1);             \
        uB.hh[hh2 * 2 + 1] = __builtin_amdgcn_cvt_pkrtz(b2, b3);             \
      }                                                                      \
      pbA[c2] = uA.v; pbB[c2] = uB.v;                                        \
    }                                                                        \
    f32x4 asumA = z, asumB = z;                                              \
    __builtin_amdgcn_s_setprio(1);                                           \
    _Pragma("unroll")                                                        \
    for (int c2 = 0; c2 < 2; c2++) {                                         \
      asumA = __builtin_amdgcn_mfma_f32_16x16x32_f16(ones8, pbA[c2], asumA, 0, 0, 0); \
      asumB = __builtin_amdgcn_mfma_f32_16x16x32_f16(ones8, pbB[c2], asumB, 0, 0, 0); \
      _Pragma("unroll")                                                      \
      for (int dt = 0; dt < 4; dt++) {                                       \
        otA[dt] = __builtin_amdgcn_mfma_f32_16x16x32_f16(vf[c2 * 4 + dt], pbA[c2], otA[dt], 0, 0, 0); \
        otB[dt] = __builtin_amdgcn_mfma_f32_16x16x32_f16(vf[c2 * 4 + dt], pbB[c2], otB[dt], 0, 0, 0); \
      }                                                                      \
    }                                                                        \
    __builtin_amdgcn_s_setprio(0);                                           \
    lA += asumA[0]; lB += asumB[0];                                          \
  }

  for (int s2 = 0; s2 < 8; s2 += 2) {
    FLASH_BODY(s2, kfP, kfQ);
    FLASH_BODY(s2 + 1, kfQ, kfP);
  }
#undef FLASH_BODY

  // ---- in-block split-K merge (waves 1-3 dump partials; wave 0 combines)
  if (wid > 0) {
    const int w = wid - 1;
#pragma unroll
    for (int dt = 0; dt < 4; dt++)
#pragma unroll
      for (int reg = 0; reg < 4; reg++) {
        smO[w][dt * 4 + reg][lane] = otA[dt][reg];
        smO[w][16 + dt * 4 + reg][lane] = otB[dt][reg];
      }
    if (quad == 0) {
      smML[w][0][lr][0] = mA; smML[w][0][lr][1] = lA;
      smML[w][1][lr][0] = mB; smML[w][1][lr][1] = lB;
    }
  }
  __syncthreads();
  if (wid == 0) {
    const float m1A = smML[0][0][lr][0], l1A = smML[0][0][lr][1];
    const float m2A = smML[1][0][lr][0], l2A = smML[1][0][lr][1];
    const float m3A = smML[2][0][lr][0], l3A = smML[2][0][lr][1];
    const float m1B = smML[0][1][lr][0], l1B = smML[0][1][lr][1];
    const float m2B = smML[1][1][lr][0], l2B = smML[1][1][lr][1];
    const float m3B = smML[2][1][lr][0], l3B = smML[2][1][lr][1];
    const float mmA = fmaxf(fmaxf(mA, m1A), fmaxf(m2A, m3A));
    const float mmB = fmaxf(fmaxf(mB, m1B), fmaxf(m2B, m3B));
    const float a0 = fexp2((mA - mmA) * SC2), a1 = fexp2((m1A - mmA) * SC2);
    const float a2 = fexp2((m2A - mmA) * SC2), a3 = fexp2((m3A - mmA) * SC2);
    const float b0 = fexp2((mB - mmB) * SC2), b1 = fexp2((m1B - mmB) * SC2);
    const float b2 = fexp2((m2B - mmB) * SC2), b3 = fexp2((m3B - mmB) * SC2);
    const float LA = a0 * lA + a1 * l1A + a2 * l2A + a3 * l3A;
    const float LB = b0 * lB + b1 * l1B + b2 * l2B + b3 * l3B;
    const float invA = 1.0f / LA, invB = 1.0f / LB;
    bf16_t* arowA = attn + ((size_t)bb * 2048 + q0 + lr) * 768 + h * 64 + g4;
    bf16_t* arowB = attn + ((size_t)bb * 2048 + q0 + 16 + lr) * 768 + h * 64 + g4;
#pragma unroll
    for (int dt = 0; dt < 4; dt++) {
      bf16x4 vA, vB;
#pragma unroll
      for (int reg = 0; reg < 4; reg++) {
        const int e = dt * 4 + reg;
        const float oA = a0 * otA[dt][reg] + a1 * smO[0][e][lane] +
                         a2 * smO[1][e][lane] + a3 * smO[2][e][lane];
        const float oB = b0 * otB[dt][reg] + b1 * smO[0][16 + e][lane] +
                         b2 * smO[1][16 + e][lane] + b3 * smO[2][16 + e][lane];
        vA[reg] = (bf16_t)(oA * invA);
        vB[reg] = (bf16_t)(oB * invB);
      }
      *(bf16x4*)(arowA + dt * 16) = vA;
      *(bf16x4*)(arowB + dt * 16) = vB;
    }
  }
}

// -------------------------------------------------- output GEMM (attn @ Wo^T)
// 64x64 tiles -> 768 blocks (3/CU), BK=64 double-buffered with
// prefetch-before-compute (two 32-k sub-tiles per slot).
__global__ __launch_bounds__(256, 3) void k_gemm2(
    const bf16_t* __restrict__ A, const bf16_t* __restrict__ Bm,
    const void* __restrict__ bo, const unsigned short* __restrict__ xdet,
    float* __restrict__ outF, unsigned short* __restrict__ outH) {
  __shared__ __align__(16) char smem[32768];  // A slots @0,8192 | B @16384,24576

  const int tid = threadIdx.x, wid = tid >> 6, lane = tid & 63;
  const int n0 = blockIdx.x * 64, m0 = blockIdx.y * 64;
  const int wm = (wid >> 1) << 5, wn = (wid & 1) << 5;
  const int lr = lane & 15, lk = (lane >> 4) << 3, g4 = (lane >> 4) << 2;
  const bf16_t* Ag = A + (size_t)(m0 + (tid >> 2)) * 768 + ((tid & 3) << 3);
  const bf16_t* Bg = Bm + (size_t)(n0 + (tid >> 2)) * 768 + ((tid & 3) << 3);

  f32x4 acc[2][2];
  const f32x4 z = {0.f, 0.f, 0.f, 0.f};
#pragma unroll
  for (int i = 0; i < 2; i++)
#pragma unroll
    for (int j = 0; j < 2; j++) acc[i][j] = z;

  {  // stage k0=0 -> slot 0 (two 32-k halves per operand)
    bf16_t* A0 = (bf16_t*)smem;
    bf16_t* B0 = (bf16_t*)(smem + 16384);
    glds16(Ag, A0 + wid * 512);
    glds16(Ag + 32, A0 + 2048 + wid * 512);
    glds16(Bg, B0 + wid * 512);
    glds16(Bg + 32, B0 + 2048 + wid * 512);
  }
  __syncthreads();

  for (int s = 0; s < 12; s++) {
    if (s < 11) {  // prefetch s+1 into other slot
      const int k0 = (s + 1) * 64;
      bf16_t* An = (bf16_t*)(smem + ((s + 1) & 1) * 8192);
      bf16_t* Bn = (bf16_t*)(smem + 16384 + ((s + 1) & 1) * 8192);
      glds16(Ag + k0, An + wid * 512);
      glds16(Ag + k0 + 32, An + 2048 + wid * 512);
      glds16(Bg + k0, Bn + wid * 512);
      glds16(Bg + k0 + 32, Bn + 2048 + wid * 512);
    }
#pragma unroll
    for (int kc = 0; kc < 2; kc++) {
      const bf16_t* As = (const bf16_t*)(smem + (s & 1) * 8192) + kc * 2048;
      const bf16_t* Bs = (const bf16_t*)(smem + 16384 + (s & 1) * 8192) + kc * 2048;
      bf16x8 af[2], bf_[2];
#pragma unroll
      for (int i = 0; i < 2; i++) af[i]  = *(const bf16x8*)&As[(wm + i * 16 + lr) * 32 + lk];
#pragma unroll
      for (int j = 0; j < 2; j++) bf_[j] = *(const bf16x8*)&Bs[(wn + j * 16 + lr) * 32 + lk];
#pragma unroll
      for (int i = 0; i < 2; i++)
#pragma unroll
        for (int j = 0; j < 2; j++)
          acc[i][j] = __builtin_amdgcn_mfma_f32_16x16x32_bf16(af[i], bf_[j], acc[i][j], 0, 0, 0);
    }
    __syncthreads();
  }

  const int obf = detect_bf16_flag(xdet);
#pragma unroll
  for (int i = 0; i < 2; i++)
#pragma unroll
    for (int j = 0; j < 2; j++) {
      const int nn = n0 + wn + j * 16 + lr;
      const float bv = obf ? bf2f(((const unsigned short*)bo)[nn])
                           : ((const float*)bo)[nn];
#pragma unroll
      for (int reg = 0; reg < 4; reg++) {
        const int m = m0 + wm + i * 16 + g4 + reg;
        const float v = acc[i][j][reg] + bv;
        if (obf) outH[(size_t)m * 768 + nn] = __builtin_bit_cast(unsigned short, (bf16_t)v);
        else     outF[(size_t)m * 768 + nn] = v;
      }
    }
}

// -------------------------------------------------------------------- launch
extern "C" void kernel_launch(void* const* d_in, const int* in_sizes, int n_in,
                              void* d_out, int out_size, void* d_ws, size_t ws_size,
                              hipStream_t stream) {
  (void)in_sizes; (void)n_in; (void)out_size; (void)ws_size;
  const void* x    = d_in[0];
  const void* mask = d_in[1];
  const void* Wq   = d_in[2];
  const void* Wk   = d_in[3];
  const void* Wv   = d_in[4];
  const void* Wo   = d_in[5];
  const void* bo   = d_in[6];

  char* w = (char*)d_ws;
  size_t off = 0;
  auto take = [&](size_t b) -> void* {
    void* p = w + off;
    off = (off + b + 255) & ~(size_t)255;
    return p;
  };
  int*      mflags = (int*)take(256 * 4);
  bf16_t*   wqkvT  = (bf16_t*)take((size_t)2304 * 768 * 2);
  bf16_t*   woT    = (bf16_t*)take((size_t)768 * 768 * 2);
  bf16_t*   xb     = (bf16_t*)take((size_t)4096 * 768 * 2);
  bf16_t*   Qd     = (bf16_t*)take((size_t)3145728 * 2);
  char*     Kd     = (char*)take((size_t)3145728 * 2);
  char*     Vt     = (char*)take((size_t)3145728 * 2);
  bf16_t*   attn   = xb;  // xb dead after QKV GEMM (flash output reuses it)

  k_prep<<<4096, 256, 0, stream>>>(x, mask, Wq, Wk, Wv, Wo, xb, wqkvT, woT, mflags);
  k_gemmQKV<<<dim3(18, 32), 256, 0, stream>>>(xb, wqkvT, Qd, Kd, Vt,
                                              (const unsigned short*)x);
  k_flash<<<1536, 256, 0, stream>>>(Qd, Kd, Vt, mask, mflags,
                                    (const unsigned short*)x, attn);
  k_gemm2<<<dim3(12, 64), 256, 0, stream>>>(attn, woT, bo, (const unsigned short*)x,
                                            (float*)d_out, (unsigned short*)d_out);
}

// Round 9
// 176.755 us; speedup vs baseline: 3.1208x; 3.1208x over previous
//
#include <hip/hip_runtime.h>

// MultiHeadSelfAttention: B=2, S=2048, E=768, H=12, D=64
// R21: R20 structure (LDS-free 4-wave in-block split-K flash) with the
//      spill fixed. R20's launch_bounds(256,4) forced VGPR=64 -> ~1.4GB of
//      scratch spill traffic per dispatch (FETCH 466MB / WRITE 887MB,
//      MfmaUtil 2.6%). The same body fit 128 VGPR spill-free in R19 under
//      a 256 cap. Single change: launch_bounds(256,2). Everything else
//      byte-identical to R20. prep/gemmQKV/gemm2 unchanged.

typedef __bf16 bf16_t;
typedef bf16_t bf16x8 __attribute__((ext_vector_type(8)));
typedef bf16_t bf16x4 __attribute__((ext_vector_type(4)));
typedef float f32x4 __attribute__((ext_vector_type(4)));
typedef _Float16 f16x4 __attribute__((ext_vector_type(4)));
typedef _Float16 f16x8 __attribute__((ext_vector_type(8)));
typedef __fp16 hf2 __attribute__((ext_vector_type(2)));

#define SC2 0.1803368801111137f  // 0.125 * log2(e): qk-scale folded into exp2
#define DEFER_THR 44.0f          // ~8/SC2: defer-max rescale threshold (T13)

__device__ __forceinline__ float bf2f(unsigned short u) {
  union { unsigned int i; float f; } x;
  x.i = ((unsigned int)u) << 16;
  return x.f;
}

__device__ __forceinline__ float fexp2(float x) {
  return __builtin_amdgcn_exp2f(x);  // raw v_exp_f32; args <= 8 here, FTZ exact
}

__device__ __forceinline__ void glds16(const bf16_t* g, bf16_t* l) {
  __builtin_amdgcn_global_load_lds(
      (const __attribute__((address_space(1))) void*)g,
      (__attribute__((address_space(3))) void*)l, 16, 0, 0);
}

// dtype probe: wave examines first 1024 u16 words of x. fp32 data => low
// halves carry random mantissa bits => wild bf16 exponents.
__device__ __forceinline__ int detect_bf16_flag(const unsigned short* x) {
  const int lane = threadIdx.x & 63;
  const uint4* p = (const uint4*)x;
  uint4 a = p[lane * 2];
  uint4 b = p[lane * 2 + 1];
  unsigned int w[8] = {a.x, a.y, a.z, a.w, b.x, b.y, b.z, b.w};
  unsigned int big = 0;
#pragma unroll
  for (int i = 0; i < 8; i++) {
    unsigned int e0 = (w[i] >> 7) & 0xFF, e1 = (w[i] >> 23) & 0xFF;
    big |= (e0 > 0x88u) | (e1 > 0x88u);
  }
  unsigned long long bal = __ballot(big != 0u);
  return bal == 0ULL ? 1 : 0;  // 1 => bf16 inputs
}

// ---------------------------------------------------------------- fused prep
__global__ void k_prep(const void* __restrict__ x, const void* __restrict__ mask,
                       const void* __restrict__ Wq, const void* __restrict__ Wk,
                       const void* __restrict__ Wv, const void* __restrict__ Wo,
                       bf16_t* __restrict__ xb, bf16_t* __restrict__ wqkvT,
                       bf16_t* __restrict__ woT, int* __restrict__ mflags) {
  __shared__ float ts[32][33];
  __shared__ int snz;
  const int blk = blockIdx.x;
  const int f = detect_bf16_flag((const unsigned short*)x);

  if (blk < 1536) {  // ---- ingest x (fp32 only; bf16 path reads x directly)
    if (f) return;
    int i = blk * 256 + threadIdx.x;
    const float* xf = (const float*)x + (size_t)i * 8;
    bf16x8 v;
#pragma unroll
    for (int j = 0; j < 8; j++) v[j] = (bf16_t)xf[j];
    *(bf16x8*)(xb + (size_t)i * 8) = v;
  } else if (blk < 3840) {  // ---- W transpose (4 matrices x 24x24 tiles)
    const int t = blk - 1536;
    const int z = t / 576, r = t % 576, kt = r / 24, nt = r % 24;
    const void* wsrc = (z == 0) ? Wq : (z == 1) ? Wk : (z == 2) ? Wv : Wo;
    bf16_t* dst = (z < 3) ? (wqkvT + (size_t)z * 768 * 768) : woT;
    const int c = threadIdx.x & 31, r0 = threadIdx.x >> 5;
#pragma unroll
    for (int i = 0; i < 4; i++) {
      int kr = kt * 32 + r0 + i * 8;
      float v;
      if (f) v = bf2f(((const unsigned short*)wsrc)[(size_t)kr * 768 + nt * 32 + c]);
      else   v = ((const float*)wsrc)[(size_t)kr * 768 + nt * 32 + c];
      ts[r0 + i * 8][c] = v;
    }
    __syncthreads();
#pragma unroll
    for (int i = 0; i < 4; i++) {
      int nr = nt * 32 + r0 + i * 8;
      dst[(size_t)nr * 768 + kt * 32 + c] = (bf16_t)ts[c][r0 + i * 8];
    }
  } else {  // ---- mask nonzero flag per 128x128 tile, uint4 loads
    const int t = blk - 3840;
    const int qt = t >> 4, ktm = t & 15;
    if (threadIdx.x == 0) snz = 0;
    __syncthreads();
    unsigned int nz = 0;
    if (f) {
#pragma unroll
      for (int i = 0; i < 8; i++) {
        int uidx = i * 256 + threadIdx.x;
        int row = uidx >> 4, col = uidx & 15;
        const uint4* p = (const uint4*)((const char*)mask +
            ((size_t)(qt * 128 + row) * 2048 + ktm * 128) * 2 + col * 16);
        uint4 v = *p;
        nz |= ((v.x | v.y | v.z | v.w) & 0x7fff7fffu);
      }
    } else {
#pragma unroll
      for (int i = 0; i < 16; i++) {
        int uidx = i * 256 + threadIdx.x;
        int row = uidx >> 5, col = uidx & 31;
        const uint4* p = (const uint4*)((const char*)mask +
            ((size_t)(qt * 128 + row) * 2048 + ktm * 128) * 4 + col * 16);
        uint4 v = *p;
        nz |= ((v.x | v.y | v.z | v.w) & 0x7fffffffu);
      }
    }
    if (nz) snz = 1;
    __syncthreads();
    if (threadIdx.x == 0) mflags[qt * 16 + ktm] = snz;
  }
}

// ------------------------------------------------------------------ QKV GEMM
// C[4096 x 2304] = A * wqkvT^T, 128x128 tile, BK=32 double-buffered with
// prefetch-before-compute. Epilogues emit flash-ready tiled layouts:
//   Kd: per (b,h,64-key group) 8KB block = permuted-slot fragment image
//   Vt: per (b,h,64-key tile) 8KB block, [64d][128B row ^ ((d&7)<<4)]
__global__ __launch_bounds__(256, 3) void k_gemmQKV(
    const bf16_t* __restrict__ xb, const bf16_t* __restrict__ Bm,
    bf16_t* __restrict__ Qd, char* __restrict__ Kd, char* __restrict__ Vt,
    const unsigned short* __restrict__ xdet) {
  __shared__ __align__(16) char smem[32768];  // A slots @0,8192 | B @16384,24576
  _Float16* Tb = (_Float16*)smem;             // V epilogue reuse (17.4KB)

  const int f = detect_bf16_flag(xdet);
  const bf16_t* A = f ? (const bf16_t*)xdet : xb;

  const int tid = threadIdx.x;
  const int n0 = blockIdx.x * 128, m0 = blockIdx.y * 128;
  const int r = tid >> 2, c8 = (tid & 3) << 3;
  const bf16_t* Ag = A + (size_t)(m0 + r) * 768 + c8;
  const bf16_t* Bg = Bm + (size_t)(n0 + r) * 768 + c8;
  const int wid = tid >> 6, lane = tid & 63;
  const int wm = (wid >> 1) << 6, wn = (wid & 1) << 6;
  const int lr = lane & 15, quad = lane >> 4, lk = quad << 3, g4 = quad << 2;

  f32x4 acc[4][4];
  const f32x4 z = {0.f, 0.f, 0.f, 0.f};
#pragma unroll
  for (int i = 0; i < 4; i++)
#pragma unroll
    for (int j = 0; j < 4; j++) acc[i][j] = z;

  {  // stage k0=0 -> slot 0
    bf16_t* A0 = (bf16_t*)smem;
    bf16_t* B0 = (bf16_t*)(smem + 16384);
    glds16(Ag, A0 + wid * 512);
    glds16(Ag + (size_t)64 * 768, A0 + 2048 + wid * 512);
    glds16(Bg, B0 + wid * 512);
    glds16(Bg + (size_t)64 * 768, B0 + 2048 + wid * 512);
  }
  __syncthreads();

  for (int s = 0; s < 24; s++) {
    if (s < 23) {  // prefetch s+1 into other slot (overlaps compute below)
      const int k0 = (s + 1) * 32;
      bf16_t* An = (bf16_t*)(smem + ((s + 1) & 1) * 8192);
      bf16_t* Bn = (bf16_t*)(smem + 16384 + ((s + 1) & 1) * 8192);
      glds16(Ag + k0, An + wid * 512);
      glds16(Ag + (size_t)64 * 768 + k0, An + 2048 + wid * 512);
      glds16(Bg + k0, Bn + wid * 512);
      glds16(Bg + (size_t)64 * 768 + k0, Bn + 2048 + wid * 512);
    }
    const bf16_t* As = (const bf16_t*)(smem + (s & 1) * 8192);
    const bf16_t* Bs = (const bf16_t*)(smem + 16384 + (s & 1) * 8192);
    bf16x8 af[4], bf_[4];
#pragma unroll
    for (int t = 0; t < 4; t++) af[t]  = *(const bf16x8*)&As[(wm + t * 16 + lr) * 32 + lk];
#pragma unroll
    for (int t = 0; t < 4; t++) bf_[t] = *(const bf16x8*)&Bs[(wn + t * 16 + lr) * 32 + lk];
#pragma unroll
    for (int i = 0; i < 4; i++)
#pragma unroll
      for (int j = 0; j < 4; j++)
        acc[i][j] = __builtin_amdgcn_mfma_f32_16x16x32_bf16(af[i], bf_[j], acc[i][j], 0, 0, 0);
    __syncthreads();  // joins waves + drains this iter's DMA (issued pre-compute)
  }

  if (n0 < 768) {  // Q: natural [seq][d] scatter
    const int bb = m0 >> 11;
#pragma unroll
    for (int i = 0; i < 4; i++)
#pragma unroll
      for (int j = 0; j < 4; j++) {
        const int rc = n0 + wn + j * 16 + lr;
        const int hh = rc >> 6, dd = rc & 63;
        const size_t base = (((size_t)bb * 12 + hh) * 2048) * 64 + dd;
#pragma unroll
        for (int reg = 0; reg < 4; reg++) {
          const int s = (m0 & 2047) + wm + i * 16 + g4 + reg;
          Qd[base + (size_t)s * 64] = (bf16_t)acc[i][j][reg];
        }
      }
  } else if (n0 < 1536) {  // K: permuted-slot tiled layout (flash fragment image)
    const int nb = n0 - 768;
    const int bb = m0 >> 11;
    const int g = ((m0 & 2047) + wm) >> 6;  // 64-key group
#pragma unroll
    for (int i = 0; i < 4; i++) {
#pragma unroll
      for (int j = 0; j < 4; j++) {
        const int rc = nb + wn + j * 16 + lr;
        const int hh = rc >> 6, dd = rc & 63;
        const size_t tbase = ((size_t)((bb * 12 + hh) * 32 + g)) << 13;
        const int doff = ((dd >> 5) << 10) + (((dd >> 3) & 3) << 8) + ((dd & 7) << 1);
#pragma unroll
        for (int reg = 0; reg < 4; reg++) {
          // slot sigma(w), w = 16i + 4*quad + reg (within-64 key index)
          const int sig = ((i >> 1) << 5) + ((quad & 1) << 4) +
                          (((((i & 1) << 1) | (quad >> 1))) << 2) + reg;
          *(bf16_t*)(Kd + tbase + ((sig >> 4) << 11) + ((sig & 15) << 4) + doff) =
              (bf16_t)acc[i][j][reg];
        }
      }
    }
  } else {  // V: LDS transpose -> tiled swizzled [64d][128B^swz] blocks
    const int bb = m0 >> 11;
#pragma unroll
    for (int half = 0; half < 2; half++) {
      if ((wid & 1) == half) {
#pragma unroll
        for (int j = 0; j < 4; j++) {
          const int d_l = j * 16 + lr;
#pragma unroll
          for (int i = 0; i < 4; i++)
#pragma unroll
            for (int reg = 0; reg < 4; reg++)
              Tb[d_l * 136 + wm + i * 16 + g4 + reg] = (_Float16)acc[i][j][reg];
        }
      }
      __syncthreads();
      const int row = tid >> 2, cc = (tid & 3) * 32;  // row = d (0..63)
      const int vcol = (n0 - 1536) + half * 64 + row;
      const int hh = vcol >> 6;
      const int g = ((m0 & 2047) + cc) >> 6;          // 64-key tile
      const int koff2 = (cc & 63) * 2;                // 0 or 64 bytes
      char* vb = Vt + (((size_t)((bb * 12 + hh) * 32 + g)) << 13) + (row << 7);
#pragma unroll
      for (int u = 0; u < 4; u++)
        *(uint4*)(vb + ((koff2 + u * 16) ^ ((row & 7) << 4))) =
            *(const uint4*)&Tb[row * 136 + cc + u * 8];
      __syncthreads();
    }
  }
}

// ----------------------------------------------------------- flash attention
// R21: 1536 blocks x 256 thr (4 waves). Block owns one (bh, 32-q-row) unit;
// wave w handles K-tiles [w*8, w*8+8) with the LDS-free body (K/V fragments
// global->VGPR from pre-permuted layouts, K prefetch 1 ahead). Partials
// (m,l,O) merged once per block through LDS (LSE-combine, exact).
// launch_bounds(256,2): 256-VGPR cap (R19 allocated 128 spill-free under
// the same cap; R20's (256,4) forced 64 VGPR -> 1.4GB scratch thrash).
__global__ __launch_bounds__(256, 2) void k_flash(
    const bf16_t* __restrict__ Qd, const char* __restrict__ Kd,
    const char* __restrict__ Vt, const void* __restrict__ mask,
    const int* __restrict__ mflags, const unsigned short* __restrict__ xdet,
    bf16_t* __restrict__ attn) {
  __shared__ float smO[3][32][64];      // waves 1-3 partial O, [elem][lane]
  __shared__ float smML[3][2][16][2];   // waves 1-3, frag A/B, row, (m,l)

  const int tid = threadIdx.x, wid = tid >> 6, lane = tid & 63;
  const int lr = lane & 15, quad = lane >> 4, lk = quad << 3, g4 = quad << 2;

  const int lin = blockIdx.x;
  const int gx = lin & 7, ww = lin >> 3;          // ww 0..191
  const int hb = gx * 3 + (ww >> 6);              // 3 bh per XCD (L2 affinity)
  const int h = hb % 12, bb = hb / 12;
  const int u = ww & 63;                          // 32-row q-unit
  const int q0 = u * 32;
  const int wtile = wid << 3;                     // this wave's first K-tile

  const size_t bh = (size_t)bb * 12 + h;
  const char* Kw = Kd + (bh << 18) + ((size_t)wtile << 13);
  const char* Vw = Vt + (bh << 18) + ((size_t)wtile << 13);

  const bf16_t* Qh = Qd + bh * 2048 * 64;
  const int mbf = detect_bf16_flag(xdet);
  const int* mfrow = mflags + (u >> 2) * 16;
  int mbits = 0;
#pragma unroll
  for (int t = 0; t < 16; t++) mbits |= (mfrow[t] != 0) << t;

  const bf16x8 qfA0 = *(const bf16x8*)&Qh[(size_t)(q0 + lr) * 64 + lk];
  const bf16x8 qfA1 = *(const bf16x8*)&Qh[(size_t)(q0 + lr) * 64 + 32 + lk];
  const bf16x8 qfB0 = *(const bf16x8*)&Qh[(size_t)(q0 + 16 + lr) * 64 + lk];
  const bf16x8 qfB1 = *(const bf16x8*)&Qh[(size_t)(q0 + 16 + lr) * 64 + 32 + lk];

  f16x8 ones8;
#pragma unroll
  for (int j = 0; j < 8; j++) ones8[j] = (_Float16)1.f;

  // V fragment offsets (per-lane constant, within 8KB tile)
  const int vxo0 = (quad * 16) ^ ((lr & 7) << 4);
  const int vxo1 = (64 + quad * 16) ^ ((lr & 7) << 4);

  const f32x4 z = {0.f, 0.f, 0.f, 0.f};
  f32x4 otA[4], otB[4];
#pragma unroll
  for (int dt = 0; dt < 4; dt++) { otA[dt] = z; otB[dt] = z; }
  float mA = -1e30f, lA = 0.f, mB = -1e30f, lB = 0.f;

  bf16x8 kfP[8], kfQ[8];
  {  // prologue: K fragments for this wave's tile 0
#pragma unroll
    for (int ct = 0; ct < 4; ct++) {
      kfP[ct * 2]     = *(const bf16x8*)(Kw + ct * 2048 + lane * 16);
      kfP[ct * 2 + 1] = *(const bf16x8*)(Kw + ct * 2048 + 1024 + lane * 16);
    }
  }

  // BODY(sl): V(sl) loads; K(sl+1)->KN; QK(sl) from KC; softmax A/B; PV.
#define FLASH_BODY(S, KC, KN)                                                \
  {                                                                          \
    const int sl_ = (S);                                                     \
    const char* Vt_ = Vw + ((size_t)sl_ << 13);                              \
    f16x8 vf[8];                                                             \
    _Pragma("unroll")                                                        \
    for (int c2 = 0; c2 < 2; c2++) {                                         \
      _Pragma("unroll")                                                      \
      for (int dt = 0; dt < 4; dt++)                                         \
        vf[c2 * 4 + dt] = *(const f16x8*)(Vt_ + (dt * 16 + lr) * 128 +       \
                                          (c2 ? vxo1 : vxo0));               \
    }                                                                        \
    if (sl_ + 1 < 8) {                                                       \
      const char* Kn_ = Kw + ((size_t)(sl_ + 1) << 13);                      \
      _Pragma("unroll")                                                      \
      for (int ct = 0; ct < 4; ct++) {                                       \
        KN[ct * 2]     = *(const bf16x8*)(Kn_ + ct * 2048 + lane * 16);      \
        KN[ct * 2 + 1] = *(const bf16x8*)(Kn_ + ct * 2048 + 1024 + lane * 16); \
      }                                                                      \
    }                                                                        \
    f32x4 svA[4], svB[4];                                                    \
    _Pragma("unroll")                                                        \
    for (int ct = 0; ct < 4; ct++) { svA[ct] = z; svB[ct] = z; }             \
    __builtin_amdgcn_s_setprio(1);                                           \
    _Pragma("unroll")                                                        \
    for (int ct = 0; ct < 4; ct++) {                                         \
      svA[ct] = __builtin_amdgcn_mfma_f32_16x16x32_bf16(KC[ct * 2], qfA0, svA[ct], 0, 0, 0); \
      svA[ct] = __builtin_amdgcn_mfma_f32_16x16x32_bf16(KC[ct * 2 + 1], qfA1, svA[ct], 0, 0, 0); \
      svB[ct] = __builtin_amdgcn_mfma_f32_16x16x32_bf16(KC[ct * 2], qfB0, svB[ct], 0, 0, 0); \
      svB[ct] = __builtin_amdgcn_mfma_f32_16x16x32_bf16(KC[ct * 2 + 1], qfB1, svB[ct], 0, 0, 0); \
    }                                                                        \
    __builtin_amdgcn_s_setprio(0);                                           \
    const int gt_ = wtile + sl_;                                             \
    if ((mbits >> (gt_ >> 1)) & 1) {                                         \
      _Pragma("unroll")                                                      \
      for (int ct = 0; ct < 4; ct++) {                                       \
        _Pragma("unroll")                                                    \
        for (int reg = 0; reg < 4; reg++) {                                  \
          const int kk = ((ct >> 1) << 5) + (quad << 3) + ((ct & 1) << 2) + reg; \
          size_t miA = (size_t)(q0 + lr) * 2048 + gt_ * 64 + kk;             \
          size_t miB = (size_t)(q0 + 16 + lr) * 2048 + gt_ * 64 + kk;        \
          float mvA = mbf ? bf2f(((const unsigned short*)mask)[miA])         \
                          : ((const float*)mask)[miA];                       \
          float mvB = mbf ? bf2f(((const unsigned short*)mask)[miB])         \
                          : ((const float*)mask)[miB];                       \
          svA[ct][reg] -= 8e9f * mvA;                                        \
          svB[ct][reg] -= 8e9f * mvB;                                        \
        }                                                                    \
      }                                                                      \
    }                                                                        \
    float tA = fmaxf(                                                        \
        fmaxf(fmaxf(fmaxf(svA[0][0], svA[0][1]), fmaxf(svA[0][2], svA[0][3])), \
              fmaxf(fmaxf(svA[1][0], svA[1][1]), fmaxf(svA[1][2], svA[1][3]))), \
        fmaxf(fmaxf(fmaxf(svA[2][0], svA[2][1]), fmaxf(svA[2][2], svA[2][3])), \
              fmaxf(fmaxf(svA[3][0], svA[3][1]), fmaxf(svA[3][2], svA[3][3])))); \
    float tB = fmaxf(                                                        \
        fmaxf(fmaxf(fmaxf(svB[0][0], svB[0][1]), fmaxf(svB[0][2], svB[0][3])), \
              fmaxf(fmaxf(svB[1][0], svB[1][1]), fmaxf(svB[1][2], svB[1][3]))), \
        fmaxf(fmaxf(fmaxf(svB[2][0], svB[2][1]), fmaxf(svB[2][2], svB[2][3])), \
              fmaxf(fmaxf(svB[3][0], svB[3][1]), fmaxf(svB[3][2], svB[3][3])))); \
    tA = fmaxf(tA, __shfl_xor(tA, 16));                                      \
    tA = fmaxf(tA, __shfl_xor(tA, 32));                                      \
    tB = fmaxf(tB, __shfl_xor(tB, 16));                                      \
    tB = fmaxf(tB, __shfl_xor(tB, 32));                                      \
    if (__ballot(tA > mA + DEFER_THR)) {                                     \
      const float mnew = fmaxf(mA, tA);                                      \
      const float alpha = fexp2((mA - mnew) * SC2);                          \
      _Pragma("unroll")                                                      \
      for (int dt = 0; dt < 4; dt++) {                                       \
        _Pragma("unroll")                                                    \
        for (int reg = 0; reg < 4; reg++) otA[dt][reg] *= alpha;             \
      }                                                                      \
      lA *= alpha; mA = mnew;                                                \
    }                                                                        \
    if (__ballot(tB > mB + DEFER_THR)) {                                     \
      const float mnew = fmaxf(mB, tB);                                      \
      const float alpha = fexp2((mB - mnew) * SC2);                          \
      _Pragma("unroll")                                                      \
      for (int dt = 0; dt < 4; dt++) {                                       \
        _Pragma("unroll")                                                    \
        for (int reg = 0; reg < 4; reg++) otB[dt][reg] *= alpha;             \
      }                                                                      \
      lB *= alpha; mB = mnew;                                                \
    }                                                                        \
    const float mSA = mA * SC2, mSB = mB * SC2;                              \
    f16x8 pbA[2], pbB[2];                                                    \
    _Pragma("unroll")                                                        \
    for (int c2 = 0; c2 < 2; c2++) {                                         \
      union { hf2 hh[4]; f16x8 v; } uA, uB;                                  \
      _Pragma("unroll")                                                      \
      for (int hh2 = 0; hh2 < 2; hh2++) {                                    \
        const int ct = c2 * 2 + hh2;                                         \
        float a0 = fexp2(fmaf(svA[ct][0], SC2, -mSA));                       \
        float a1 = fexp2(fmaf(svA[ct][1], SC2, -mSA));                       \
        float a2 = fexp2(fmaf(svA[ct][2], SC2, -mSA));                       \
        float a3 = fexp2(fmaf(svA[ct][3], SC2, -mSA));                       \
        float b0 = fexp2(fmaf(svB[ct][0], SC2, -mSB));                       \
        float b1 = fexp2(fmaf(svB[ct][1], SC2, -mSB));                       \
        float b2 = fexp2(fmaf(svB[ct][2], SC2, -mSB));                       \
        float b3 = fexp2(fmaf(svB[ct][3], SC2, -mSB));                       \
        uA.hh[hh2 * 2 + 0] = __builtin_amdgcn_cvt_pkrtz(a0, a1);             \
        uA.hh[hh2 * 2 + 1] = __builtin_amdgcn_cvt_pkrtz(a2, a3);             \
        uB.hh[hh2 * 2 + 0] = __builtin_amdgcn_cvt_pkrtz(b0, b1);             \
        uB.hh[hh2 * 2 + 1] = __builtin_amdgcn_cvt_pkrtz(b2, b3);             \
      }                                                                      \
      pbA[c2] = uA.v; pbB[c2] = uB.v;                                        \
    }                                                                        \
    f32x4 asumA = z, asumB = z;                                              \
    __builtin_amdgcn_s_setprio(1);                                           \
    _Pragma("unroll")                                                        \
    for (int c2 = 0; c2 < 2; c2++) {                                         \
      asumA = __builtin_amdgcn_mfma_f32_16x16x32_f16(ones8, pbA[c2], asumA, 0, 0, 0); \
      asumB = __builtin_amdgcn_mfma_f32_16x16x32_f16(ones8, pbB[c2], asumB, 0, 0, 0); \
      _Pragma("unroll")                                                      \
      for (int dt = 0; dt < 4; dt++) {                                       \
        otA[dt] = __builtin_amdgcn_mfma_f32_16x16x32_f16(vf[c2 * 4 + dt], pbA[c2], otA[dt], 0, 0, 0); \
        otB[dt] = __builtin_amdgcn_mfma_f32_16x16x32_f16(vf[c2 * 4 + dt], pbB[c2], otB[dt], 0, 0, 0); \
      }                                                                      \
    }                                                                        \
    __builtin_amdgcn_s_setprio(0);                                           \
    lA += asumA[0]; lB += asumB[0];                                          \
  }

  for (int s2 = 0; s2 < 8; s2 += 2) {
    FLASH_BODY(s2, kfP, kfQ);
    FLASH_BODY(s2 + 1, kfQ, kfP);
  }
#undef FLASH_BODY

  // ---- in-block split-K merge (waves 1-3 dump partials; wave 0 combines)
  if (wid > 0) {
    const int w = wid - 1;
#pragma unroll
    for (int dt = 0; dt < 4; dt++)
#pragma unroll
      for (int reg = 0; reg < 4; reg++) {
        smO[w][dt * 4 + reg][lane] = otA[dt][reg];
        smO[w][16 + dt * 4 + reg][lane] = otB[dt][reg];
      }
    if (quad == 0) {
      smML[w][0][lr][0] = mA; smML[w][0][lr][1] = lA;
      smML[w][1][lr][0] = mB; smML[w][1][lr][1] = lB;
    }
  }
  __syncthreads();
  if (wid == 0) {
    const float m1A = smML[0][0][lr][0], l1A = smML[0][0][lr][1];
    const float m2A = smML[1][0][lr][0], l2A = smML[1][0][lr][1];
    const float m3A = smML[2][0][lr][0], l3A = smML[2][0][lr][1];
    const float m1B = smML[0][1][lr][0], l1B = smML[0][1][lr][1];
    const float m2B = smML[1][1][lr][0], l2B = smML[1][1][lr][1];
    const float m3B = smML[2][1][lr][0], l3B = smML[2][1][lr][1];
    const float mmA = fmaxf(fmaxf(mA, m1A), fmaxf(m2A, m3A));
    const float mmB = fmaxf(fmaxf(mB, m1B), fmaxf(m2B, m3B));
    const float a0 = fexp2((mA - mmA) * SC2), a1 = fexp2((m1A - mmA) * SC2);
    const float a2 = fexp2((m2A - mmA) * SC2), a3 = fexp2((m3A - mmA) * SC2);
    const float b0 = fexp2((mB - mmB) * SC2), b1 = fexp2((m1B - mmB) * SC2);
    const float b2 = fexp2((m2B - mmB) * SC2), b3 = fexp2((m3B - mmB) * SC2);
    const float LA = a0 * lA + a1 * l1A + a2 * l2A + a3 * l3A;
    const float LB = b0 * lB + b1 * l1B + b2 * l2B + b3 * l3B;
    const float invA = 1.0f / LA, invB = 1.0f / LB;
    bf16_t* arowA = attn + ((size_t)bb * 2048 + q0 + lr) * 768 + h * 64 + g4;
    bf16_t* arowB = attn + ((size_t)bb * 2048 + q0 + 16 + lr) * 768 + h * 64 + g4;
#pragma unroll
    for (int dt = 0; dt < 4; dt++) {
      bf16x4 vA, vB;
#pragma unroll
      for (int reg = 0; reg < 4; reg++) {
        const int e = dt * 4 + reg;
        const float oA = a0 * otA[dt][reg] + a1 * smO[0][e][lane] +
                         a2 * smO[1][e][lane] + a3 * smO[2][e][lane];
        const float oB = b0 * otB[dt][reg] + b1 * smO[0][16 + e][lane] +
                         b2 * smO[1][16 + e][lane] + b3 * smO[2][16 + e][lane];
        vA[reg] = (bf16_t)(oA * invA);
        vB[reg] = (bf16_t)(oB * invB);
      }
      *(bf16x4*)(arowA + dt * 16) = vA;
      *(bf16x4*)(arowB + dt * 16) = vB;
    }
  }
}

// -------------------------------------------------- output GEMM (attn @ Wo^T)
// 64x64 tiles -> 768 blocks (3/CU), BK=64 double-buffered with
// prefetch-before-compute (two 32-k sub-tiles per slot).
__global__ __launch_bounds__(256, 3) void k_gemm2(
    const bf16_t* __restrict__ A, const bf16_t* __restrict__ Bm,
    const void* __restrict__ bo, const unsigned short* __restrict__ xdet,
    float* __restrict__ outF, unsigned short* __restrict__ outH) {
  __shared__ __align__(16) char smem[32768];  // A slots @0,8192 | B @16384,24576

  const int tid = threadIdx.x, wid = tid >> 6, lane = tid & 63;
  const int n0 = blockIdx.x * 64, m0 = blockIdx.y * 64;
  const int wm = (wid >> 1) << 5, wn = (wid & 1) << 5;
  const int lr = lane & 15, lk = (lane >> 4) << 3, g4 = (lane >> 4) << 2;
  const bf16_t* Ag = A + (size_t)(m0 + (tid >> 2)) * 768 + ((tid & 3) << 3);
  const bf16_t* Bg = Bm + (size_t)(n0 + (tid >> 2)) * 768 + ((tid & 3) << 3);

  f32x4 acc[2][2];
  const f32x4 z = {0.f, 0.f, 0.f, 0.f};
#pragma unroll
  for (int i = 0; i < 2; i++)
#pragma unroll
    for (int j = 0; j < 2; j++) acc[i][j] = z;

  {  // stage k0=0 -> slot 0 (two 32-k halves per operand)
    bf16_t* A0 = (bf16_t*)smem;
    bf16_t* B0 = (bf16_t*)(smem + 16384);
    glds16(Ag, A0 + wid * 512);
    glds16(Ag + 32, A0 + 2048 + wid * 512);
    glds16(Bg, B0 + wid * 512);
    glds16(Bg + 32, B0 + 2048 + wid * 512);
  }
  __syncthreads();

  for (int s = 0; s < 12; s++) {
    if (s < 11) {  // prefetch s+1 into other slot
      const int k0 = (s + 1) * 64;
      bf16_t* An = (bf16_t*)(smem + ((s + 1) & 1) * 8192);
      bf16_t* Bn = (bf16_t*)(smem + 16384 + ((s + 1) & 1) * 8192);
      glds16(Ag + k0, An + wid * 512);
      glds16(Ag + k0 + 32, An + 2048 + wid * 512);
      glds16(Bg + k0, Bn + wid * 512);
      glds16(Bg + k0 + 32, Bn + 2048 + wid * 512);
    }
#pragma unroll
    for (int kc = 0; kc < 2; kc++) {
      const bf16_t* As = (const bf16_t*)(smem + (s & 1) * 8192) + kc * 2048;
      const bf16_t* Bs = (const bf16_t*)(smem + 16384 + (s & 1) * 8192) + kc * 2048;
      bf16x8 af[2], bf_[2];
#pragma unroll
      for (int i = 0; i < 2; i++) af[i]  = *(const bf16x8*)&As[(wm + i * 16 + lr) * 32 + lk];
#pragma unroll
      for (int j = 0; j < 2; j++) bf_[j] = *(const bf16x8*)&Bs[(wn + j * 16 + lr) * 32 + lk];
#pragma unroll
      for (int i = 0; i < 2; i++)
#pragma unroll
        for (int j = 0; j < 2; j++)
          acc[i][j] = __builtin_amdgcn_mfma_f32_16x16x32_bf16(af[i], bf_[j], acc[i][j], 0, 0, 0);
    }
    __syncthreads();
  }

  const int obf = detect_bf16_flag(xdet);
#pragma unroll
  for (int i = 0; i < 2; i++)
#pragma unroll
    for (int j = 0; j < 2; j++) {
      const int nn = n0 + wn + j * 16 + lr;
      const float bv = obf ? bf2f(((const unsigned short*)bo)[nn])
                           : ((const float*)bo)[nn];
#pragma unroll
      for (int reg = 0; reg < 4; reg++) {
        const int m = m0 + wm + i * 16 + g4 + reg;
        const float v = acc[i][j][reg] + bv;
        if (obf) outH[(size_t)m * 768 + nn] = __builtin_bit_cast(unsigned short, (bf16_t)v);
        else     outF[(size_t)m * 768 + nn] = v;
      }
    }
}

// -------------------------------------------------------------------- launch
extern "C" void kernel_launch(void* const* d_in, const int* in_sizes, int n_in,
                              void* d_out, int out_size, void* d_ws, size_t ws_size,
                              hipStream_t stream) {
  (void)in_sizes; (void)n_in; (void)out_size; (void)ws_size;
  const void* x    = d_in[0];
  const void* mask = d_in[1];
  const void* Wq   = d_in[2];
  const void* Wk   = d_in[3];
  const void* Wv   = d_in[4];
  const void* Wo   = d_in[5];
  const void* bo   = d_in[6];

  char* w = (char*)d_ws;
  size_t off = 0;
  auto take = [&](size_t b) -> void* {
    void* p = w + off;
    off = (off + b + 255) & ~(size_t)255;
    return p;
  };
  int*      mflags = (int*)take(256 * 4);
  bf16_t*   wqkvT  = (bf16_t*)take((size_t)2304 * 768 * 2);
  bf16_t*   woT    = (bf16_t*)take((size_t)768 * 768 * 2);
  bf16_t*   xb     = (bf16_t*)take((size_t)4096 * 768 * 2);
  bf16_t*   Qd     = (bf16_t*)take((size_t)3145728 * 2);
  char*     Kd     = (char*)take((size_t)3145728 * 2);
  char*     Vt     = (char*)take((size_t)3145728 * 2);
  bf16_t*   attn   = xb;  // xb dead after QKV GEMM (flash output reuses it)

  k_prep<<<4096, 256, 0, stream>>>(x, mask, Wq, Wk, Wv, Wo, xb, wqkvT, woT, mflags);
  k_gemmQKV<<<dim3(18, 32), 256, 0, stream>>>(xb, wqkvT, Qd, Kd, Vt,
                                              (const unsigned short*)x);
  k_flash<<<1536, 256, 0, stream>>>(Qd, Kd, Vt, mask, mflags,
                                    (const unsigned short*)x, attn);
  k_gemm2<<<dim3(12, 64), 256, 0, stream>>>(attn, woT, bo, (const unsigned short*)x,
                                            (float*)d_out, (unsigned short*)d_out);
}